// Round 6
// baseline (310.291 us; speedup 1.0000x reference)
//
#include <hip/hip_runtime.h>
#include <hip/hip_fp16.h>

typedef _Float16 f16;
typedef _Float16 f16x8 __attribute__((ext_vector_type(8)));
typedef _Float16 f16x4 __attribute__((ext_vector_type(4)));
typedef float f32x4 __attribute__((ext_vector_type(4)));

#define DEV static __device__ __forceinline__
#define VMCNT(n) asm volatile("s_waitcnt vmcnt(" #n ")" ::: "memory")

DEV void barfence() {
    __builtin_amdgcn_s_barrier();
    asm volatile("" ::: "memory");
}

DEV void async_copy16(const f16* gsrc, f16* ldst) {
    __builtin_amdgcn_global_load_lds(
        (const __attribute__((address_space(1))) void*)gsrc,
        (__attribute__((address_space(3))) void*)ldst,
        16, 0, 0);
}
DEV void async_copy4(const f16* gsrc, f16* ldst) {
    __builtin_amdgcn_global_load_lds(
        (const __attribute__((address_space(1))) void*)gsrc,
        (__attribute__((address_space(3))) void*)ldst,
        4, 0, 0);
}

// ---------------------------------------------------------------------------
// fp32 -> f16 convert, grid-stride over float4s
__global__ void convert_f16_k(const float* __restrict__ src, f16* __restrict__ dst, int n4) {
    for (int idx = blockIdx.x * 256 + threadIdx.x; idx < n4; idx += gridDim.x * 256) {
        float4 v = reinterpret_cast<const float4*>(src)[idx];
        f16x4 o;
        o[0] = (f16)v.x; o[1] = (f16)v.y; o[2] = (f16)v.z; o[3] = (f16)v.w;
        *reinterpret_cast<f16x4*>(dst + (size_t)idx * 4) = o;
    }
}

// ---------------------------------------------------------------------------
// local [16][l][d] fp32 -> localF [16][l][1024] f16 and localT [16][d][1024 l] f16
__global__ void split_local_k(const float* __restrict__ local,
                              f16* __restrict__ localF, f16* __restrict__ localT) {
    __shared__ float tile[64][65];
    const int b  = blockIdx.z;
    const int l0 = blockIdx.y * 64;
    const int d0 = blockIdx.x * 64;
    const int r  = threadIdx.x >> 4;   // 0..15
    const int c4 = threadIdx.x & 15;   // 0..15
    const float* src = local + ((size_t)b * 1024 + l0) * 1024 + d0;
    #pragma unroll
    for (int rr = 0; rr < 4; rr++) {
        int row = rr * 16 + r;
        float4 v = *reinterpret_cast<const float4*>(src + (size_t)row * 1024 + c4 * 4);
        float vv[4] = {v.x, v.y, v.z, v.w};
        f16x4 hv;
        #pragma unroll
        for (int e = 0; e < 4; e++) {
            tile[row][c4 * 4 + e] = vv[e];
            hv[e] = (f16)vv[e];
        }
        *reinterpret_cast<f16x4*>(localF + ((size_t)b * 1024 + l0 + row) * 1024 + d0 + c4 * 4) = hv;
    }
    __syncthreads();
    #pragma unroll
    for (int rr = 0; rr < 4; rr++) {
        int d = rr * 16 + r;
        f16x4 o;
        #pragma unroll
        for (int e = 0; e < 4; e++) o[e] = (f16)tile[c4 * 4 + e][d];
        *reinterpret_cast<f16x4*>(localT + ((size_t)b * 1024 + d0 + d) * 1024 + l0 + c4 * 4) = o;
    }
}

// ---------------------------------------------------------------------------
// 256x256 tile GEMM (proj, PV) — unchanged known-good structure.
DEV void load_af(const f16* lds, int base, int c0, int c1, f16x8 (&a)[4][2]) {
    #pragma unroll
    for (int i = 0; i < 4; i++) {
        a[i][0] = *reinterpret_cast<const f16x8*>(&lds[base + i * 1024 + c0]);
        a[i][1] = *reinterpret_cast<const f16x8*>(&lds[base + i * 1024 + c1]);
    }
}
DEV void load_bf(const f16* lds, int base, int c0, int c1, f16x8 (&b)[2][2]) {
    #pragma unroll
    for (int j = 0; j < 2; j++) {
        b[j][0] = *reinterpret_cast<const f16x8*>(&lds[base + j * 1024 + c0]);
        b[j][1] = *reinterpret_cast<const f16x8*>(&lds[base + j * 1024 + c1]);
    }
}
template <int Q>
DEV void mfma16(const f16x8 (&a)[4][2], const f16x8 (&b)[2][2], f32x4 (&acc)[4][4][2]) {
    __builtin_amdgcn_s_setprio(1);
    #pragma unroll
    for (int i = 0; i < 4; i++)
        #pragma unroll
        for (int j = 0; j < 2; j++) {
            acc[Q][i][j] = __builtin_amdgcn_mfma_f32_16x16x32_f16(a[i][0], b[j][0], acc[Q][i][j], 0, 0, 0);
            acc[Q][i][j] = __builtin_amdgcn_mfma_f32_16x16x32_f16(a[i][1], b[j][1], acc[Q][i][j], 0, 0, 0);
        }
    __builtin_amdgcn_s_setprio(0);
}

template <int EPI>
__launch_bounds__(512)
__global__ void gemm256_k(const f16* __restrict__ A, const f16* __restrict__ B,
                          float* __restrict__ Cf, f16* __restrict__ Cs,
                          const float* __restrict__ bias,
                          int N, int K, long sA, long sB, long sC, int nbn) {
    extern __shared__ f16 lds[];   // 128 KiB
    const int nwg  = gridDim.x;
    const int cpx  = nwg >> 3;
    const int wgid = (blockIdx.x & 7) * cpx + (blockIdx.x >> 3);
    const int per_b = (EPI == 0) ? nwg : 16;
    const int bz  = wgid / per_b;
    const int rem = wgid % per_b;
    const int bm  = rem / nbn;
    const int bn  = rem % nbn;

    const int tid  = threadIdx.x;
    const int lane = tid & 63;
    const int w    = tid >> 6;
    const int wr   = w >> 2, wc = w & 3;
    const f16* Ab = A + (size_t)bz * sA + (size_t)(bm * 256) * K;
    const f16* Bb = B + (size_t)bz * sB + (size_t)(bn * 256) * K;
    const int rloc = lane >> 3;
    const int sl8  = ((lane & 7) ^ rloc) * 8;
    const int lrow = lane & 15;
    const int c0 = (8 * (lane >> 4)) ^ (8 * (lane & 7));
    const int c1 = c0 ^ 32;
    const int abase = (wr * 64 + lrow) * 64;
    const int bbase = (wc * 32 + lrow) * 64;

    auto stageA = [&](int sb, int half, int k0) {
        #pragma unroll
        for (int i = 0; i < 2; i++) {
            int rr = (w * 2 + i) * 8 + rloc;
            async_copy16(Ab + (size_t)(half * 128 + rr) * K + k0 + sl8,
                         &lds[sb + half * 8192 + (w * 2 + i) * 512 + lane * 8]);
        }
    };
    auto stageB = [&](int sb, int half, int k0) {
        #pragma unroll
        for (int i = 0; i < 2; i++) {
            int rr = (w * 2 + i) * 8 + rloc;
            async_copy16(Bb + (size_t)(half * 128 + rr) * K + k0 + sl8,
                         &lds[sb + 16384 + half * 8192 + (w * 2 + i) * 512 + lane * 8]);
        }
    };

    f32x4 acc[4][4][2] = {};
    const int nt = K >> 6;

    stageA(0, 0, 0); stageB(0, 0, 0);
    stageB(0, 1, 0); stageA(0, 1, 0);
    VMCNT(4);
    barfence();

    for (int t = 0; t < nt - 1; ++t) {
        const int cb = (t & 1) * 32768;
        const int sb = cb ^ 32768;
        const int kn = (t + 1) * 64;
        f16x8 af[4][2], bf0[2][2], bf1[2][2];
        load_af(lds, cb + abase, c0, c1, af);
        load_bf(lds, cb + 16384 + bbase, c0, c1, bf0);
        stageA(sb, 0, kn); stageB(sb, 0, kn);
        barfence();
        mfma16<0>(af, bf0, acc);
        VMCNT(6);
        barfence();
        load_bf(lds, cb + 16384 + 8192 + bbase, c0, c1, bf1);
        stageB(sb, 1, kn);
        barfence();
        mfma16<1>(af, bf1, acc);
        VMCNT(6);
        barfence();
        load_af(lds, cb + 8192 + abase, c0, c1, af);
        stageA(sb, 1, kn);
        barfence();
        mfma16<2>(af, bf0, acc);
        mfma16<3>(af, bf1, acc);
        VMCNT(4);
        barfence();
    }
    {
        const int cb = ((nt - 1) & 1) * 32768;
        f16x8 af[4][2], bf0[2][2], bf1[2][2];
        load_af(lds, cb + abase, c0, c1, af);
        load_bf(lds, cb + 16384 + bbase, c0, c1, bf0);
        barfence();
        mfma16<0>(af, bf0, acc);
        VMCNT(2);
        barfence();
        load_bf(lds, cb + 16384 + 8192 + bbase, c0, c1, bf1);
        barfence();
        mfma16<1>(af, bf1, acc);
        VMCNT(0);
        barfence();
        load_af(lds, cb + 8192 + abase, c0, c1, af);
        barfence();
        mfma16<2>(af, bf0, acc);
        mfma16<3>(af, bf1, acc);
    }

    const int r4 = (lane >> 4) * 4, cl = lane & 15;
    #pragma unroll
    for (int q = 0; q < 4; q++)
        #pragma unroll
        for (int i = 0; i < 4; i++)
            #pragma unroll
            for (int j = 0; j < 2; j++) {
                const int row0 = bm * 256 + (q >> 1) * 128 + wr * 64 + i * 16 + r4;
                const int col  = bn * 256 + (q & 1) * 128 + wc * 32 + j * 16 + cl;
                if constexpr (EPI == 0) {
                    float bv = bias[col];
                    #pragma unroll
                    for (int r = 0; r < 4; r++) {
                        float v = acc[q][i][j][r] + bv;
                        Cs[(size_t)(row0 + r) * N + col] = (f16)v;
                    }
                } else {
                    #pragma unroll
                    for (int r = 0; r < 4; r++)
                        Cf[(size_t)bz * sC + (size_t)(row0 + r) * N + col] = acc[q][i][j][r];
                }
            }
}

// ---------------------------------------------------------------------------
// Fused scores+softmax: per block, S-rows = 64 (BM), full N=1024 (BN), K=1024.
// 8 waves split N (128 cols each). BK=32, double-buffered LDS:
//   buf: [A 64x32 (2048 f16) | B 1024x32 (32768 f16, half-permuted rows)]
// writes attn = f16(softmax(S)) directly.
DEV void mfma_q(const f16x8 (&a)[4], const f16x8 (&b)[4], f32x4 (&acc)[4][8], int h) {
    __builtin_amdgcn_s_setprio(1);
    #pragma unroll
    for (int i = 0; i < 4; i++)
        #pragma unroll
        for (int jj = 0; jj < 4; jj++)
            acc[i][h * 4 + jj] = __builtin_amdgcn_mfma_f32_16x16x32_f16(a[i], b[jj], acc[i][h * 4 + jj], 0, 0, 0);
    __builtin_amdgcn_s_setprio(0);
}

__launch_bounds__(512)
__global__ void fused_sm_k(const f16* __restrict__ projF, const f16* __restrict__ localF,
                           f16* __restrict__ attn) {
    extern __shared__ f16 lds[];          // 2 x 34816 f16 = 136 KiB
    const int wgid = (blockIdx.x & 7) * 32 + (blockIdx.x >> 3);   // XCD swizzle (256 wgs)
    const int bz = wgid >> 4, bm = wgid & 15;
    const int tid = threadIdx.x, lane = tid & 63, w = tid >> 6;
    const int lrow = lane & 15, lslot = lane >> 4;
    const f16* Pa = projF + ((size_t)bz * 1024 + bm * 64) * 1024;
    const f16* Lb = localF + (size_t)bz * 1024 * 1024;
    const int BUF = 34816;

    auto stageA = [&](int sb, int k0) {   // 2 width-4 issues/thread, all waves
        #pragma unroll
        for (int q = 0; q < 2; q++) {
            int row = q * 32 + (tid >> 4);
            int s   = (tid >> 2) & 3;
            int w2  = (tid & 3) * 2;
            async_copy4(Pa + (size_t)row * 1024 + k0 + (s ^ ((row >> 1) & 3)) * 8 + w2,
                        &lds[sb + q * 1024 + tid * 2]);
        }
    };
    auto stageB = [&](int sb, int h, int k0) {  // 4 width-16 issues/thread
        #pragma unroll
        for (int q = 0; q < 4; q++) {
            int widx = q * 128 + (tid >> 2);
            int r    = (widx >> 6) * 128 + h * 64 + (widx & 63);
            int slot = tid & 3;
            async_copy16(Lb + (size_t)r * 1024 + k0 + ((slot ^ ((r >> 1) & 3)) * 8),
                         &lds[sb + 2048 + h * 16384 + q * 4096 + tid * 8]);
        }
    };
    auto ldA = [&](int cb, f16x8 (&a)[4]) {
        #pragma unroll
        for (int i = 0; i < 4; i++) {
            int row = i * 16 + lrow;
            a[i] = *reinterpret_cast<const f16x8*>(
                &lds[cb + row * 32 + ((lslot ^ ((row >> 1) & 3)) * 8)]);
        }
    };
    auto ldB = [&](int cb, int h, f16x8 (&b)[4]) {
        #pragma unroll
        for (int jj = 0; jj < 4; jj++) {
            int r    = w * 128 + h * 64 + jj * 16 + lrow;
            int widx = w * 64 + jj * 16 + lrow;
            b[jj] = *reinterpret_cast<const f16x8*>(
                &lds[cb + 2048 + h * 16384 + widx * 32 + ((lslot ^ ((r >> 1) & 3)) * 8)]);
        }
    };

    f32x4 acc[4][8] = {};

    // prologue: A, B-h0, B-h1 of tile 0 -> wait A+B0, leave B1 in flight
    stageA(0, 0); stageB(0, 0, 0); stageB(0, 1, 0);
    VMCNT(4);
    barfence();

    for (int t = 0; t < 31; ++t) {
        const int cb = (t & 1) * BUF, sb = cb ^ BUF;
        const int kn = (t + 1) * 32;
        f16x8 a[4], b[4];
        ldA(cb, a); ldB(cb, 0, b);
        stageA(sb, kn); stageB(sb, 0, kn);
        barfence();
        mfma_q(a, b, acc, 0);
        VMCNT(6);            // completes this tile's B1
        barfence();
        ldB(cb, 1, b);
        stageB(sb, 1, kn);
        barfence();
        mfma_q(a, b, acc, 1);
        VMCNT(4);            // completes next tile's A + B0
        barfence();
    }
    {   // peeled t=31
        const int cb = BUF;
        f16x8 a[4], b[4];
        ldA(cb, a); ldB(cb, 0, b);
        barfence();
        mfma_q(a, b, acc, 0);
        VMCNT(0);
        barfence();
        ldB(cb, 1, b);
        barfence();
        mfma_q(a, b, acc, 1);
    }

    // ---- in-block row softmax (rows block-local: BN = 1024) ----
    barfence();
    float* red = (float*)lds;   // [64][8] partials, [512..576) max, [576..640) inv
    #pragma unroll
    for (int i = 0; i < 4; i++)
        #pragma unroll
        for (int rr = 0; rr < 4; rr++) {
            float m = acc[i][0][rr];
            #pragma unroll
            for (int j = 1; j < 8; j++) m = fmaxf(m, acc[i][j][rr]);
            #pragma unroll
            for (int off = 1; off < 16; off <<= 1) m = fmaxf(m, __shfl_xor(m, off));
            if (lrow == 0) red[(i * 16 + lslot * 4 + rr) * 8 + w] = m;
        }
    barfence();
    if (tid < 64) {
        float m = red[tid * 8];
        #pragma unroll
        for (int k = 1; k < 8; k++) m = fmaxf(m, red[tid * 8 + k]);
        red[512 + tid] = m;
    }
    barfence();
    #pragma unroll
    for (int i = 0; i < 4; i++)
        #pragma unroll
        for (int rr = 0; rr < 4; rr++) {
            int row = i * 16 + lslot * 4 + rr;
            float fm = red[512 + row];
            float s = 0.f;
            #pragma unroll
            for (int j = 0; j < 8; j++) {
                float e = __expf(acc[i][j][rr] - fm);
                acc[i][j][rr] = e;
                s += e;
            }
            #pragma unroll
            for (int off = 1; off < 16; off <<= 1) s += __shfl_xor(s, off);
            if (lrow == 0) red[row * 8 + w] = s;
        }
    barfence();
    if (tid < 64) {
        float s = 0.f;
        #pragma unroll
        for (int k = 0; k < 8; k++) s += red[tid * 8 + k];
        red[576 + tid] = 1.0f / s;
    }
    barfence();
    f16* Ob = attn + ((size_t)bz * 1024 + bm * 64) * 1024;
    #pragma unroll
    for (int i = 0; i < 4; i++)
        #pragma unroll
        for (int rr = 0; rr < 4; rr++) {
            int row = i * 16 + lslot * 4 + rr;
            float inv = red[576 + row];
            #pragma unroll
            for (int j = 0; j < 8; j++)
                Ob[(size_t)row * 1024 + w * 128 + j * 16 + lrow] = (f16)(acc[i][j][rr] * inv);
        }
}

// ---------------------------------------------------------------------------
extern "C" void kernel_launch(void* const* d_in, const int* in_sizes, int n_in,
                              void* d_out, int out_size, void* d_ws, size_t ws_size,
                              hipStream_t stream) {
    const float* text  = (const float*)d_in[0];  // [16,1024,1024]
    const float* local = (const float*)d_in[1];  // [16,1024,1024]
    const float* Ww    = (const float*)d_in[2];  // [1024,1024]
    const float* Wb    = (const float*)d_in[3];  // [1024]
    float* out = (float*)d_out;                  // [16,1024,1024] fp32

    char* ws = (char*)d_ws;
    const size_t MB = 1024 * 1024;
    f16* textF  = (f16*)(ws);                 // 32MB
    f16* WF     = (f16*)(ws + 32 * MB);       //  2MB
    f16* localF = (f16*)(ws + 36 * MB);       // 32MB
    f16* localT = (f16*)(ws + 68 * MB);       // 32MB
    f16* projF  = (f16*)(ws + 100 * MB);      // 32MB
    f16* attn   = (f16*)(ws + 132 * MB);      // 32MB

    auto g0 = gemm256_k<0>;
    auto g1 = gemm256_k<1>;
    (void)hipFuncSetAttribute((const void*)g0, hipFuncAttributeMaxDynamicSharedMemorySize, 131072);
    (void)hipFuncSetAttribute((const void*)g1, hipFuncAttributeMaxDynamicSharedMemorySize, 131072);
    (void)hipFuncSetAttribute((const void*)fused_sm_k, hipFuncAttributeMaxDynamicSharedMemorySize, 139264);

    hipLaunchKernelGGL(convert_f16_k, dim3(2048), dim3(256), 0, stream, text, textF, 16384 * 256);
    hipLaunchKernelGGL(convert_f16_k, dim3(512), dim3(256), 0, stream, Ww, WF, 1024 * 256);
    hipLaunchKernelGGL(split_local_k, dim3(16, 16, 16), dim3(256), 0, stream,
                       local, localF, localT);
    // proj = f16(text @ W^T + b)  (M=16384, N=1024, K=1024)
    hipLaunchKernelGGL(g0, dim3(256), dim3(512), 131072, stream,
                       textF, WF, (float*)nullptr, projF, Wb,
                       1024, 1024, 0L, 0L, 0L, 4);
    // attn[b] = softmax(proj[b] @ local[b]^T)  fused
    hipLaunchKernelGGL(fused_sm_k, dim3(256), dim3(512), 139264, stream,
                       projF, localF, attn);
    // out[b] = attn[b] @ local[b]  (K=1024)
    hipLaunchKernelGGL(g1, dim3(256), dim3(512), 131072, stream,
                       attn, localT, out, (f16*)nullptr, (const float*)nullptr,
                       1024, 1024, (long)1024 * 1024, (long)1024 * 1024, (long)1024 * 1024, 4);
}